// Round 7
// baseline (239.129 us; speedup 1.0000x reference)
//
#include <hip/hip_runtime.h>

#define N_NEUR 512
#define B_SZ   16
#define T_STEPS 32
#define NIN    32
#define NOUT   16
#define CAPC   84   // chem nnz/row cap (mean 48.6, sd 6.63)
#define CAPG   52   // gj nnz/row cap   (mean 25.6, sd 4.93)
#define MC2    46   // register slots per thread, chem (max half-list 42 + slack)
#define MG2    30   // register slots per thread, gj   (max half-list 26 + slack)
#define MCP2   23   // packed col words, chem
#define MGP2   15   // packed col words, gj
#define LOG2E  1.4426950408889634f

__device__ __forceinline__ float rcp_fast(float x) {
#if __has_builtin(__builtin_amdgcn_rcpf)
    return __builtin_amdgcn_rcpf(x);
#else
    return 1.0f / x;
#endif
}
__device__ __forceinline__ float exp2_fast(float x) {
#if __has_builtin(__builtin_amdgcn_exp2f)
    return __builtin_amdgcn_exp2f(x);
#else
    return exp2f(x);
#endif
}

// prep1: per row, softplus + mask + ballot-compact into per-row CSR
// (split col/weight arrays to shrink workspace).
__global__ __launch_bounds__(64) void prep1_kernel(
    const float* __restrict__ W,
    const float* __restrict__ mex,
    const float* __restrict__ min_,
    const float* __restrict__ mgj,
    int* __restrict__ key_arr, int* __restrict__ ccA, int* __restrict__ cgA,
    float* __restrict__ tmpCw, short* __restrict__ tmpCc,
    float* __restrict__ tmpGw, short* __restrict__ tmpGc)
{
    const int row  = blockIdx.x;
    const int lane = threadIdx.x;
    const unsigned long long below = (1ull << lane) - 1ull;
    int bc = 0, bg = 0;
    for (int c0 = 0; c0 < N_NEUR; c0 += 64) {
        const int col = c0 + lane;
        const int off = row * N_NEUR + col;
        const float w  = W[off];
        const float sp = fmaxf(w, 0.0f) + log1pf(__expf(-fabsf(w)));  // softplus
        const float dm = mex[off] - min_[off];                         // in {-1,0,1}
        bool a = (dm != 0.0f);
        unsigned long long m = __ballot(a);
        int idx = bc + __popcll(m & below);
        if (a && idx < CAPC) {
            tmpCw[row * CAPC + idx] = sp * dm;
            tmpCc[row * CAPC + idx] = (short)col;
        }
        bc += __popcll(m);

        const float g = mgj[off];
        bool ag = (g != 0.0f);
        m = __ballot(ag);
        idx = bg + __popcll(m & below);
        if (ag && idx < CAPG) {
            tmpGw[row * CAPG + idx] = sp * g;
            tmpGc[row * CAPG + idx] = (short)col;
        }
        bg += __popcll(m);
    }
    if (lane == 0) {
        int cc = min(bc, CAPC), cg = min(bg, CAPG);
        ccA[row] = cc; cgA[row] = cg; key_arr[row] = cc + cg;
    }
}

// rank: order[rank] = d, rank by (nnz asc, index) so waves hold similar counts.
__global__ __launch_bounds__(64) void rank_kernel(
    const int* __restrict__ key_arr, int* __restrict__ order)
{
    const int d    = blockIdx.x;
    const int lane = threadIdx.x;
    const int kd   = key_arr[d];
    int r = 0;
    for (int j = lane; j < N_NEUR; j += 64) {
        int kj = key_arr[j];
        r += (kj < kd) || (kj == kd && j < d);
    }
    #pragma unroll
    for (int i = 1; i < 64; i <<= 1) r += __shfl_xor(r, i);
    if (lane == 0) order[r] = d;
}

// greedy: one block (1 wave) per main-kernel wave. Closed-loop bank-aware
// slot assignment: per slot, each lane proposes its first remaining entry;
// commit if that bank's load < 2 (2-way aliasing is free on gfx950), else
// try its second remaining entry, else leave the slot empty (col 0 ->
// broadcast, weight 0). Force-commit when slots run low guarantees
// completion. Emits the transposed register-load layout + per-wave slot
// counts for the main kernel's guards.
__global__ __launch_bounds__(64) void greedy_kernel(
    const int* __restrict__ order, const int* __restrict__ ccA, const int* __restrict__ cgA,
    const float* __restrict__ tmpCw, const short* __restrict__ tmpCc,
    const float* __restrict__ tmpGw, const short* __restrict__ tmpGc,
    float* __restrict__ wCt, unsigned* __restrict__ cpCt,
    float* __restrict__ wGt, unsigned* __restrict__ cpGt,
    int* __restrict__ nCarr, int* __restrict__ nGarr)
{
    __shared__ float wL[64][MC2];     // per-lane entry weights
    __shared__ short cL[64][MC2];     // per-lane entry cols
    __shared__ short slotc[64][MC2];  // committed col per slot
    __shared__ int   propcnt[32];

    const int w = blockIdx.x;
    const int L = threadIdx.x;
    const int r = w * 32 + (L >> 1);
    const int h = L & 1;
    const int d = order[r];

    #pragma unroll
    for (int pass = 0; pass < 2; ++pass) {
        const int  cnt = pass ? cgA[d] : ccA[d];
        const int  CAP = pass ? CAPG : CAPC;
        const int  M   = pass ? MG2  : MC2;
        const int  MP  = pass ? MGP2 : MCP2;
        const float* tw = pass ? tmpGw : tmpCw;
        const short* tc = pass ? tmpGc : tmpCc;
        float*    wT = pass ? wGt  : wCt;
        unsigned* cT = pass ? cpGt : cpCt;

        const int m = (cnt + 1 - h) >> 1;          // this lane's entries
        for (int j = 0; j < m; ++j) {
            wL[L][j] = tw[d * CAP + 2 * j + h];
            cL[L][j] = tc[d * CAP + 2 * j + h];
        }
        unsigned long long rem = (m >= 64) ? ~0ull : ((1ull << m) - 1ull);
        int kmax = 0;

        for (int k = 0; k < M; ++k) {
            if (L < 32) propcnt[L] = 0;
            int myc = 0; float myw = 0.0f; bool committed = false;
            if (rem) {
                int j0 = (int)__ffsll((unsigned long long)rem) - 1;
                int c0 = cL[L][j0]; int b0 = c0 & 31;
                bool force = (M - k) <= __popcll(rem);
                int p0 = atomicAdd(&propcnt[b0], 1);
                if (force || p0 < 2) {
                    myc = c0; myw = wL[L][j0]; rem &= ~(1ull << j0); committed = true;
                } else {
                    unsigned long long rem2 = rem & ~(1ull << j0);
                    if (rem2) {
                        int j1 = (int)__ffsll(rem2) - 1;
                        int c1 = cL[L][j1]; int b1 = c1 & 31;
                        int p1 = atomicAdd(&propcnt[b1], 1);
                        if (p1 < 2) {
                            myc = c1; myw = wL[L][j1]; rem &= ~(1ull << j1); committed = true;
                        }
                    }
                }
            }
            slotc[L][k] = (short)myc;
            wT[(w * M + k) * 64 + L] = myw;
            if (__ballot(committed)) kmax = k;
        }
        for (int kp = 0; kp < MP; ++kp) {
            unsigned c0 = ((unsigned)(unsigned short)slotc[L][2 * kp])     << 2;
            unsigned c1 = ((unsigned)(unsigned short)slotc[L][2 * kp + 1]) << 2;
            cT[(w * MP + kp) * 64 + L] = c0 | (c1 << 16);
        }
        if (L == 0) { if (pass) nGarr[w] = kmax + 1; else nCarr[w] = kmax + 1; }
        __syncthreads();   // harmless; separates passes
    }
}

#define CHEM_K(k, A) {                                                      \
    unsigned pk = cpC[(k) >> 1];                                            \
    unsigned off = ((k) & 1) ? (pk >> 16) : (pk & 0xffffu);                 \
    A = fmaf(wC[k], *(const float*)((const char*)ObP + off), A); }

#define CHEM_C4(a) { CHEM_K(a, accA) CHEM_K((a)+1, accB) CHEM_K((a)+2, accA) CHEM_K((a)+3, accB) }

#define GJ_K(k, A) {                                                        \
    unsigned pk = cpG[(k) >> 1];                                            \
    unsigned off = ((k) & 1) ? (pk >> 16) : (pk & 0xffffu);                 \
    float Os = *(const float*)((const char*)ObP + off);                     \
    float f = fmaf(20.0f * LOG2E, Os, cE);                                  \
    float tnh = 1.0f - 2.0f * rcp_fast(1.0f + exp2_fast(f));                \
    A = fmaf(wG[k] * Os, tnh, A); }

#define GJ_C4(a) { GJ_K(a, accA) GJ_K((a)+1, accB) GJ_K((a)+2, accA) GJ_K((a)+3, accB) }

// main: one block per batch, 1024 threads = 2 per neuron (sorted by nnz).
// Lists in registers (greedy bank-scheduled slots); fixed-trip unrolled
// chunks with wave-uniform scalar guards; one barrier per step.
__global__ __launch_bounds__(1024, 1) void recur_kernel(
    const float* __restrict__ obs,
    const float* __restrict__ thr,
    const float* __restrict__ dec,
    const int* __restrict__ order,
    const int* __restrict__ nCarr, const int* __restrict__ nGarr,
    const float* __restrict__ wCt, const unsigned* __restrict__ cpCt,
    const float* __restrict__ wGt, const unsigned* __restrict__ cpGt,
    float* __restrict__ out)
{
    __shared__ float Ob[2][N_NEUR];
    __shared__ float Eb[2][N_NEUR];

    const int b    = blockIdx.x;
    const int tid  = threadIdx.x;
    const int h    = tid & 1;
    const int r    = tid >> 1;            // rank
    const int wv   = tid >> 6;
    const int lane = tid & 63;

    const int d = order[r];
    const float thr_d = thr[d];
    const float dec_d = dec[d];

    const int mCw = __builtin_amdgcn_readfirstlane(nCarr[wv]);
    const int mGw = __builtin_amdgcn_readfirstlane(nGarr[wv]);

    // register-resident greedy-scheduled lists (empty slots: w=0, col=0)
    float wC[MC2]; unsigned cpC[MCP2];
    float wG[MG2]; unsigned cpG[MGP2];
    #pragma unroll
    for (int k = 0; k < MC2; ++k)  wC[k]  = wCt[(wv * MC2 + k) * 64 + lane];
    #pragma unroll
    for (int k = 0; k < MCP2; ++k) cpC[k] = cpCt[(wv * MCP2 + k) * 64 + lane];
    #pragma unroll
    for (int k = 0; k < MG2; ++k)  wG[k]  = wGt[(wv * MG2 + k) * 64 + lane];
    #pragma unroll
    for (int k = 0; k < MGP2; ++k) cpG[k] = cpGt[(wv * MGP2 + k) * 64 + lane];

    const bool inj = (h == 0) && (d < NIN);
    const bool wr  = (h == 0) && (d >= NIN) && (d < NIN + NOUT);
    float* outp = out + (size_t)b * T_STEPS * NOUT + (d - NIN);
    const float* obs_b = obs + b * (T_STEPS * NIN);

    if (h == 0) {
        float v = (d < NIN) ? obs_b[d] : 0.0f;   // state 0 = zeros + obs_0
        Ob[0][d] = v;
        Eb[0][d] = v;
    }
    int p = 0;
    __syncthreads();

    for (int t = 0; t < T_STEPS; ++t) {
        // prefetch obs_{t+1} (written into the next buffer at this step's end)
        float ob_next = (inj && (t + 1 < T_STEPS)) ? obs_b[(t + 1) * NIN + d] : 0.0f;

        const float* ObP = Ob[p];
        const float E_d = Eb[p][d];
        float accA = 0.0f, accB = 0.0f;
        // chem: chunks of 4, wave-uniform scalar guards, constant reg indices
        CHEM_C4(0)
        if ( 4 < mCw) CHEM_C4(4)
        if ( 8 < mCw) CHEM_C4(8)
        if (12 < mCw) CHEM_C4(12)
        if (16 < mCw) CHEM_C4(16)
        if (20 < mCw) CHEM_C4(20)
        if (24 < mCw) CHEM_C4(24)
        if (28 < mCw) CHEM_C4(28)
        if (32 < mCw) CHEM_C4(32)
        if (36 < mCw) CHEM_C4(36)
        if (40 < mCw) CHEM_C4(40)
        if (44 < mCw) { CHEM_K(44, accA) CHEM_K(45, accB) }
        // gj
        const float cE = -20.0f * LOG2E * E_d;
        GJ_C4(0)
        if ( 4 < mGw) GJ_C4(4)
        if ( 8 < mGw) GJ_C4(8)
        if (12 < mGw) GJ_C4(12)
        if (16 < mGw) GJ_C4(16)
        if (20 < mGw) GJ_C4(20)
        if (24 < mGw) GJ_C4(24)
        if (28 < mGw) { GJ_K(28, accA) GJ_K(29, accB) }

        float acc = accA + accB;
        acc += __shfl_xor(acc, 1);

        // epilogue (both halves compute; h==0 writes)
        float curr = fminf(fmaxf(E_d + acc, -10.0f), 10.0f);
        float z = curr - thr_d;
        float O_new = (z >= 0.0f) ? z : 0.01f * z;
        float fg = rcp_fast(1.0f + exp2_fast(-10.0f * LOG2E * z));
        float dg = rcp_fast(1.0f + exp2_fast(-5.0f * LOG2E * (fabsf(E_d - curr) - 0.01f)));
        float E_nf  = dg * curr + (1.0f - dg) * (E_d - dec_d);
        float E_new = fg * O_new + (1.0f - fg) * E_nf;

        const int q = p ^ 1;
        if (h == 0) {
            Eb[q][d] = inj ? ob_next : E_new;
            Ob[q][d] = inj ? ob_next : O_new;
            if (wr) outp[t * NOUT] = E_new;
        }
        __syncthreads();
        p = q;
    }
}

extern "C" void kernel_launch(void* const* d_in, const int* in_sizes, int n_in,
                              void* d_out, int out_size, void* d_ws, size_t ws_size,
                              hipStream_t stream)
{
    const float* obs  = (const float*)d_in[0];
    const float* W    = (const float*)d_in[1];
    const float* thr  = (const float*)d_in[2];
    const float* dec  = (const float*)d_in[3];
    const float* mex  = (const float*)d_in[4];
    const float* min_ = (const float*)d_in[5];
    const float* mgj  = (const float*)d_in[6];
    float* out = (float*)d_out;

    char* ws = (char*)d_ws;
    int*   key_arr = (int*)(ws);                     // 2048
    int*   ccA     = (int*)(ws + 2048);              // 2048
    int*   cgA     = (int*)(ws + 4096);              // 2048
    int*   order   = (int*)(ws + 6144);              // 2048
    int*   nCarr   = (int*)(ws + 8192);              // 64
    int*   nGarr   = (int*)(ws + 8256);              // 64
    float* tmpCw   = (float*)(ws + 12288);           // 512*84*4 = 172032
    short* tmpCc   = (short*)(ws + 184320);          // 512*84*2 =  86016
    float* tmpGw   = (float*)(ws + 270336);          // 512*52*4 = 106496
    short* tmpGc   = (short*)(ws + 376832);          // 512*52*2 =  53248
    float* wCt     = (float*)(ws + 430080);          // 16*46*64*4 = 188416
    unsigned* cpCt = (unsigned*)(ws + 618496);       // 16*23*64*4 =  94208
    float* wGt     = (float*)(ws + 712704);          // 16*30*64*4 = 122880
    unsigned* cpGt = (unsigned*)(ws + 835584);       // 16*15*64*4 =  61440
    // total ws use: 897024 B

    prep1_kernel<<<N_NEUR, 64, 0, stream>>>(W, mex, min_, mgj,
                                            key_arr, ccA, cgA,
                                            tmpCw, tmpCc, tmpGw, tmpGc);
    rank_kernel<<<N_NEUR, 64, 0, stream>>>(key_arr, order);
    greedy_kernel<<<16, 64, 0, stream>>>(order, ccA, cgA,
                                         tmpCw, tmpCc, tmpGw, tmpGc,
                                         wCt, cpCt, wGt, cpGt, nCarr, nGarr);
    recur_kernel<<<B_SZ, 1024, 0, stream>>>(obs, thr, dec,
                                            order, nCarr, nGarr,
                                            wCt, cpCt, wGt, cpGt, out);
}